// Round 1
// baseline (232.132 us; speedup 1.0000x reference)
//
#include <hip/hip_runtime.h>

#define NB 32
#define NN 64
#define ND 128
#define NE 128

// workspace layout (bytes)
static constexpr size_t U_BYTES  = (size_t)NB * NN * NN * ND * 4; // 67108864
static constexpr size_t V_BYTES  = (size_t)NB * NN * ND * 4;      // 1048576
static constexpr size_t WS_NEED  = U_BYTES + 2 * V_BYTES;

// ---------------- DPP wave64 reductions (VALU pipe, no LDS) ----------------
template <int CTRL, int RMASK>
__device__ __forceinline__ float dppf(float x) {
    int xi = __float_as_int(x);
    return __int_as_float(
        __builtin_amdgcn_update_dpp(xi, xi, CTRL, RMASK, 0xF, false));
}

__device__ __forceinline__ float wave_max(float x) {
    x = fmaxf(x, dppf<0xB1, 0xF>(x));   // quad_perm [1,0,3,2]
    x = fmaxf(x, dppf<0x4E, 0xF>(x));   // quad_perm [2,3,0,1]
    x = fmaxf(x, dppf<0x141, 0xF>(x));  // row_half_mirror
    x = fmaxf(x, dppf<0x140, 0xF>(x));  // row_mirror
    x = fmaxf(x, dppf<0x142, 0xA>(x));  // row_bcast15 -> rows 1,3
    x = fmaxf(x, dppf<0x143, 0xC>(x));  // row_bcast31 -> rows 2,3
    return __int_as_float(__builtin_amdgcn_readlane(__float_as_int(x), 63));
}

__device__ __forceinline__ float wave_sum(float x) {
    x += dppf<0xB1, 0xF>(x);
    x += dppf<0x4E, 0xF>(x);
    x += dppf<0x141, 0xF>(x);
    x += dppf<0x140, 0xF>(x);
    x += dppf<0x142, 0xA>(x);
    x += dppf<0x143, 0xC>(x);
    return __int_as_float(__builtin_amdgcn_readlane(__float_as_int(x), 63));
}

// ---------------- K1: u[b,j,k,d] = sum_e W[j,k,d,e] * x[b,j,e] -------------
// grid 4096 = (j,k); 128 threads; per-thread tile 4b x 8d; fp32 VALU.
__global__ __launch_bounds__(128) void k_u(const float* __restrict__ W,
                                           const float* __restrict__ x,
                                           float* __restrict__ u) {
    __shared__ float Xs[NB * 132];  // 32 x 128, stride 132 (bank-spread)
    __shared__ float Ws[ND * 68];   // 128 x 64 e-chunk, stride 68

    const int j  = blockIdx.x >> 6;
    const int k  = blockIdx.x & 63;
    const int t  = threadIdx.x;
    const int td = t & 15;   // 16 d-groups (d = td + 16*ii)
    const int tb = t >> 4;   // 8 b-groups (b = tb*4 + bb)

    const float* Wjk = W + (size_t)(j * NN + k) * (ND * NE);

    // stage X: x[:, j, :]  (1024 float4, 8 per thread)
#pragma unroll
    for (int l = 0; l < 8; ++l) {
        int f   = (l * 128 + t) * 4;
        int b   = f >> 7;
        int col = f & 127;
        float4 v = *reinterpret_cast<const float4*>(x + (size_t)(b * NN + j) * NE + col);
        *reinterpret_cast<float4*>(&Xs[b * 132 + col]) = v;
    }

    float acc[4][8];
#pragma unroll
    for (int bb = 0; bb < 4; ++bb)
#pragma unroll
        for (int ii = 0; ii < 8; ++ii) acc[bb][ii] = 0.0f;

    for (int ec = 0; ec < 2; ++ec) {
        __syncthreads();
        // stage W rows, e in [ec*64, ec*64+64): 2048 float4, 16 per thread
#pragma unroll
        for (int l = 0; l < 16; ++l) {
            int f   = (l * 128 + t) * 4;  // 0..8191 within chunk
            int row = f >> 6;
            int col = f & 63;
            float4 v = *reinterpret_cast<const float4*>(
                Wjk + (size_t)row * NE + ec * 64 + col);
            *reinterpret_cast<float4*>(&Ws[row * 68 + col]) = v;
        }
        __syncthreads();
#pragma unroll
        for (int e = 0; e < 64; e += 4) {
            float4 xf[4], wf[8];
#pragma unroll
            for (int bb = 0; bb < 4; ++bb)
                xf[bb] = *reinterpret_cast<const float4*>(
                    &Xs[(tb * 4 + bb) * 132 + ec * 64 + e]);
#pragma unroll
            for (int ii = 0; ii < 8; ++ii)
                wf[ii] = *reinterpret_cast<const float4*>(
                    &Ws[(td + 16 * ii) * 68 + e]);
#pragma unroll
            for (int bb = 0; bb < 4; ++bb)
#pragma unroll
                for (int ii = 0; ii < 8; ++ii) {
                    acc[bb][ii] = fmaf(xf[bb].x, wf[ii].x, acc[bb][ii]);
                    acc[bb][ii] = fmaf(xf[bb].y, wf[ii].y, acc[bb][ii]);
                    acc[bb][ii] = fmaf(xf[bb].z, wf[ii].z, acc[bb][ii]);
                    acc[bb][ii] = fmaf(xf[bb].w, wf[ii].w, acc[bb][ii]);
                }
        }
    }

    // write u[b, j, k, d]; lanes td=0..15 at fixed ii cover a 64B line
    float* ujk = u + (size_t)(j * NN + k) * ND;
#pragma unroll
    for (int bb = 0; bb < 4; ++bb) {
        int b = tb * 4 + bb;
        float* ub = ujk + (size_t)b * (NN * NN * ND);
#pragma unroll
        for (int ii = 0; ii < 8; ++ii) ub[td + 16 * ii] = acc[bb][ii];
    }
}

// ---------------- Routing pass: s[b,k,d] = sum_j softmax_k(u*Vsum) * u -----
// grid 256 = (b, dtile of 16 d); 512 threads = 8 waves (2 j-halves x 4 d-quads)
// lane = k. Vsum==0 gives the uniform first iteration automatically.
__global__ __launch_bounds__(512) void k_route(const float* __restrict__ u,
                                               const float* __restrict__ Vsum,
                                               float* __restrict__ s) {
    const int b    = blockIdx.x >> 3;
    const int dt   = blockIdx.x & 7;
    const int t    = threadIdx.x;
    const int w    = t >> 6;
    const int lane = t & 63;  // = k
    const int jh   = w >> 2;
    const int dq   = w & 3;
    const int d0   = dt * 16 + dq * 4;

    const float4 vs =
        *reinterpret_cast<const float4*>(Vsum + (size_t)(b * NN + lane) * ND + d0);

    float sa0 = 0.f, sa1 = 0.f, sa2 = 0.f, sa3 = 0.f;

    const float* ub = u + (size_t)b * (NN * NN * ND) + (size_t)lane * ND + d0;
    const int j0 = jh * 32;
    for (int j = j0; j < j0 + 32; ++j) {
        float4 uv = *reinterpret_cast<const float4*>(ub + (size_t)j * (NN * ND));
        float t0 = uv.x * vs.x, t1 = uv.y * vs.y, t2 = uv.z * vs.z, t3 = uv.w * vs.w;
        float m0 = wave_max(t0), m1 = wave_max(t1), m2 = wave_max(t2), m3 = wave_max(t3);
        float p0 = __expf(t0 - m0), p1 = __expf(t1 - m1);
        float p2 = __expf(t2 - m2), p3 = __expf(t3 - m3);
        float q0 = wave_sum(p0), q1 = wave_sum(p1), q2 = wave_sum(p2), q3 = wave_sum(p3);
        sa0 = fmaf(p0 * __builtin_amdgcn_rcpf(q0), uv.x, sa0);
        sa1 = fmaf(p1 * __builtin_amdgcn_rcpf(q1), uv.y, sa1);
        sa2 = fmaf(p2 * __builtin_amdgcn_rcpf(q2), uv.z, sa2);
        sa3 = fmaf(p3 * __builtin_amdgcn_rcpf(q3), uv.w, sa3);
    }

    __shared__ float Sp[8][64][4];
    Sp[w][lane][0] = sa0;
    Sp[w][lane][1] = sa1;
    Sp[w][lane][2] = sa2;
    Sp[w][lane][3] = sa3;
    __syncthreads();

    // reduce the two j-halves and write s[b, k, dt*16 + 0..15]
    const int k   = t >> 3;
    const int dd0 = (t & 7) * 2;
    const int dd1 = dd0 + 1;
    float r0 = Sp[(dd0 >> 2)][k][dd0 & 3] + Sp[4 + (dd0 >> 2)][k][dd0 & 3];
    float r1 = Sp[(dd1 >> 2)][k][dd1 & 3] + Sp[4 + (dd1 >> 2)][k][dd1 & 3];
    float2 o = make_float2(r0, r1);
    *reinterpret_cast<float2*>(s + (size_t)(b * NN + k) * ND + dt * 16 + dd0) = o;
}

// ---------------- Squash: v = s * (sq/(1+sq)) / sqrt(sq+eps) ---------------
// one wave per (b,k); accumulates Vsum (iters 0,1) or writes output (iter 2)
__global__ __launch_bounds__(256) void k_squash(const float* __restrict__ s,
                                                float* __restrict__ Vsum,
                                                float* __restrict__ out,
                                                int last) {
    const int t    = threadIdx.x;
    const int wid  = blockIdx.x * 4 + (t >> 6);
    const int b    = wid >> 6;
    const int k    = wid & 63;
    const int lane = t & 63;

    const size_t off = (size_t)(b * NN + k) * ND + lane * 2;
    const float2 sv = *reinterpret_cast<const float2*>(s + off);
    float sq = wave_sum(sv.x * sv.x + sv.y * sv.y);
    float scale = (sq / (1.0f + sq)) * rsqrtf(sq + 1e-9f);
    float2 v = make_float2(sv.x * scale, sv.y * scale);
    if (last) {
        *reinterpret_cast<float2*>(out + off) = v;
    } else {
        float2 c = *reinterpret_cast<float2*>(Vsum + off);
        c.x += v.x;
        c.y += v.y;
        *reinterpret_cast<float2*>(Vsum + off) = c;
    }
}

extern "C" void kernel_launch(void* const* d_in, const int* in_sizes, int n_in,
                              void* d_out, int out_size, void* d_ws, size_t ws_size,
                              hipStream_t stream) {
    (void)in_sizes; (void)n_in; (void)out_size;
    const float* x = (const float*)d_in[0];
    const float* W = (const float*)d_in[1];
    float* out = (float*)d_out;

    if (ws_size < WS_NEED) return;  // fails loudly via validation
    char* ws = (char*)d_ws;
    float* u    = (float*)ws;
    float* Vsum = (float*)(ws + U_BYTES);
    float* s    = (float*)(ws + U_BYTES + V_BYTES);

    hipMemsetAsync(Vsum, 0, V_BYTES, stream);
    k_u<<<dim3(NN * NN), dim3(128), 0, stream>>>(W, x, u);
    for (int it = 0; it < 3; ++it) {
        k_route<<<dim3(256), dim3(512), 0, stream>>>(u, Vsum, s);
        k_squash<<<dim3(512), dim3(256), 0, stream>>>(s, Vsum, out, it == 2);
    }
}

// Round 2
// 196.963 us; speedup vs baseline: 1.1786x; 1.1786x over previous
//
#include <hip/hip_runtime.h>

#define NB 32
#define NN 64
#define ND 128
#define NE 128
#define NK 64   // output capsules (= NN), contiguous axis of u/Vsum/s

typedef float  f32x4  __attribute__((ext_vector_type(4)));
typedef short  short8 __attribute__((ext_vector_type(8)));
typedef __bf16 bf16x8 __attribute__((ext_vector_type(8)));

union Frag { bf16x8 h; short8 s; };

static constexpr size_t U_BYTES = (size_t)NB * NN * ND * NK * 2;  // 33.5 MB bf16
static constexpr size_t V_BYTES = (size_t)NB * ND * NK * 4;       // 1 MB fp32
static constexpr size_t WS_NEED = U_BYTES + 2 * V_BYTES;

// ---------------- DPP wave64 reductions (VALU pipe) ----------------
template <int CTRL, int RMASK>
__device__ __forceinline__ float dppf(float x) {
    int xi = __float_as_int(x);
    return __int_as_float(__builtin_amdgcn_update_dpp(xi, xi, CTRL, RMASK, 0xF, false));
}
__device__ __forceinline__ float wave_max(float x) {
    x = fmaxf(x, dppf<0xB1, 0xF>(x));
    x = fmaxf(x, dppf<0x4E, 0xF>(x));
    x = fmaxf(x, dppf<0x141, 0xF>(x));
    x = fmaxf(x, dppf<0x140, 0xF>(x));
    x = fmaxf(x, dppf<0x142, 0xA>(x));
    x = fmaxf(x, dppf<0x143, 0xC>(x));
    return __int_as_float(__builtin_amdgcn_readlane(__float_as_int(x), 63));
}
__device__ __forceinline__ float wave_sum(float x) {
    x += dppf<0xB1, 0xF>(x);
    x += dppf<0x4E, 0xF>(x);
    x += dppf<0x141, 0xF>(x);
    x += dppf<0x140, 0xF>(x);
    x += dppf<0x142, 0xA>(x);
    x += dppf<0x143, 0xC>(x);
    return __int_as_float(__builtin_amdgcn_readlane(__float_as_int(x), 63));
}

__device__ __forceinline__ ushort f2bf(float f) {
    __bf16 h = (__bf16)f;
    ushort r;
    __builtin_memcpy(&r, &h, 2);
    return r;
}
__device__ __forceinline__ float bf2f(ushort r) {
    return __int_as_float(((int)r) << 16);
}
__device__ __forceinline__ void cvt8(const float4& a, const float4& b, Frag& fr) {
    fr.h[0] = (__bf16)a.x; fr.h[1] = (__bf16)a.y; fr.h[2] = (__bf16)a.z; fr.h[3] = (__bf16)a.w;
    fr.h[4] = (__bf16)b.x; fr.h[5] = (__bf16)b.y; fr.h[6] = (__bf16)b.z; fr.h[7] = (__bf16)b.w;
}

// ---------------- K1: u[b,j,d,k] = sum_e x[b,j,e] * W[j,k,d,e] (bf16 MFMA) --
// wave = (j,d): M=32 b's x N=64 k's, K=128 e's -> 32 x mfma 16x16x32_bf16
__global__ __launch_bounds__(256) void k_u(const float* __restrict__ W,
                                           const float* __restrict__ x,
                                           ushort* __restrict__ u) {
    __shared__ ushort T[4][32][72];  // per-wave [b][k] transpose tile (stride 72: 16B-aligned rows)
    const int t  = threadIdx.x;
    const int wv = t >> 6;
    const int l  = t & 63;
    const int gw = blockIdx.x * 4 + wv;
    const int j  = gw >> 7;
    const int d  = gw & 127;

    const int lr = l & 15;        // fragment row/col index
    const int e0 = (l >> 4) * 8;  // e-offset within K=32 chunk

    const float* xb = x + (size_t)j * NE;                     // + b*(NN*NE) + e
    const float* Wb = W + ((size_t)(j * NN) * ND + d) * NE;   // + k*(ND*NE) + e

    // A fragments: x[b, j, e], row = b
    Frag a[2][4];
#pragma unroll
    for (int mt = 0; mt < 2; ++mt)
#pragma unroll
        for (int ec = 0; ec < 4; ++ec) {
            const float* p = xb + (size_t)(mt * 16 + lr) * (NN * NE) + ec * 32 + e0;
            float4 f0 = *reinterpret_cast<const float4*>(p);
            float4 f1 = *reinterpret_cast<const float4*>(p + 4);
            cvt8(f0, f1, a[mt][ec]);
        }

    f32x4 acc[2][4];
#pragma unroll
    for (int mt = 0; mt < 2; ++mt)
#pragma unroll
        for (int nt = 0; nt < 4; ++nt) acc[mt][nt] = (f32x4)0.0f;

    // B fragments streamed from W (nontemporal: zero reuse, keep L3 for u)
#pragma unroll
    for (int nt = 0; nt < 4; ++nt) {
        Frag bw[4];
#pragma unroll
        for (int ec = 0; ec < 4; ++ec) {
            const float* p = Wb + (size_t)(nt * 16 + lr) * (ND * NE) + ec * 32 + e0;
            f32x4 g0 = __builtin_nontemporal_load(reinterpret_cast<const f32x4*>(p));
            f32x4 g1 = __builtin_nontemporal_load(reinterpret_cast<const f32x4*>(p + 4));
            float4 f0 = {g0[0], g0[1], g0[2], g0[3]};
            float4 f1 = {g1[0], g1[1], g1[2], g1[3]};
            cvt8(f0, f1, bw[ec]);
        }
#pragma unroll
        for (int ec = 0; ec < 4; ++ec)
#pragma unroll
            for (int mt = 0; mt < 2; ++mt)
                acc[mt][nt] = __builtin_amdgcn_mfma_f32_16x16x32_bf16(
                    a[mt][ec].s, bw[ec].s, acc[mt][nt], 0, 0, 0);
    }

    // D frag: row=b=(l>>4)*4+r (+16*mt), col=k=lr (+16*nt)  [m89 layout]
    const int lq = l >> 4;
#pragma unroll
    for (int mt = 0; mt < 2; ++mt)
#pragma unroll
        for (int nt = 0; nt < 4; ++nt)
#pragma unroll
            for (int r = 0; r < 4; ++r)
                T[wv][mt * 16 + lq * 4 + r][nt * 16 + lr] = f2bf(acc[mt][nt][r]);
    __syncthreads();

    // write u[b, j, d, :] rows (k-contiguous, 128 B/row, lane-pairs coalesced)
    const int b2 = l >> 1;
    const int kh = (l & 1) * 32;
    ushort* up = u + (((size_t)b2 * NN + j) * ND + d) * NK + kh;
    const ushort* tp = &T[wv][b2][kh];
#pragma unroll
    for (int i = 0; i < 4; ++i) {
        short8 v = *reinterpret_cast<const short8*>(tp + i * 8);
        *reinterpret_cast<short8*>(up + i * 8) = v;
    }
}

// ---------------- Routing: s[b,d,k] = sum_j softmax_k(u*Vsum) * u ----------
// block = (b, dg of 8 d); 8 waves = 8 j-groups; lane = k
__global__ __launch_bounds__(512) void k_route(const ushort* __restrict__ u,
                                               const float* __restrict__ Vsum,
                                               float* __restrict__ s) {
    __shared__ float P[8][8][65];
    const int b  = blockIdx.x >> 4;
    const int dg = blockIdx.x & 15;
    const int t  = threadIdx.x;
    const int wv = t >> 6;  // j-group
    const int l  = t & 63;  // k

    float vs[8];
#pragma unroll
    for (int dd = 0; dd < 8; ++dd)
        vs[dd] = Vsum[((size_t)b * ND + dg * 8 + dd) * NK + l];

    float sacc[8];
#pragma unroll
    for (int dd = 0; dd < 8; ++dd) sacc[dd] = 0.0f;

    const ushort* ub = u + (((size_t)b * NN + wv * 8) * ND + dg * 8) * NK + l;
    for (int jj = 0; jj < 8; ++jj) {
        const ushort* up = ub + (size_t)jj * (ND * NK);
        float uv[8];
#pragma unroll
        for (int dd = 0; dd < 8; ++dd) uv[dd] = bf2f(up[dd * NK]);
#pragma unroll
        for (int dd = 0; dd < 8; ++dd) {
            float tt = uv[dd] * vs[dd];
            float m  = wave_max(tt);
            float p  = __expf(tt - m);
            float q  = wave_sum(p);
            sacc[dd] = fmaf(p * __builtin_amdgcn_rcpf(q), uv[dd], sacc[dd]);
        }
    }

#pragma unroll
    for (int dd = 0; dd < 8; ++dd) P[wv][dd][l] = sacc[dd];
    __syncthreads();

    // 8-way j-group reduce; thread t -> (dd = t>>6, k = t&63)
    const int dd = t >> 6;
    const int k  = t & 63;
    float r = P[0][dd][k];
#pragma unroll
    for (int w2 = 1; w2 < 8; ++w2) r += P[w2][dd][k];
    s[((size_t)b * ND + dg * 8 + dd) * NK + k] = r;
}

// ---------------- Squash: wave=(b,k), lane=d -------------------------------
__global__ __launch_bounds__(256) void k_squash(const float* __restrict__ s,
                                                float* __restrict__ Vsum,
                                                float* __restrict__ out,
                                                int last) {
    const int t  = threadIdx.x;
    const int gw = blockIdx.x * 4 + (t >> 6);
    const int b  = gw >> 6;
    const int k  = gw & 63;
    const int l  = t & 63;

    const float s0 = s[((size_t)b * ND + l) * NK + k];
    const float s1 = s[((size_t)b * ND + l + 64) * NK + k];
    float sq    = wave_sum(fmaf(s0, s0, s1 * s1));
    float scale = (sq / (1.0f + sq)) * rsqrtf(sq + 1e-9f);
    float v0 = s0 * scale, v1 = s1 * scale;
    if (last) {
        float* op = out + ((size_t)b * NN + k) * ND;  // out[b,k,d] contiguous in d
        op[l]      = v0;
        op[l + 64] = v1;
    } else {
        float* vp = Vsum + (size_t)b * ND * NK + k;
        vp[(size_t)l * NK]        += v0;
        vp[(size_t)(l + 64) * NK] += v1;
    }
}

extern "C" void kernel_launch(void* const* d_in, const int* in_sizes, int n_in,
                              void* d_out, int out_size, void* d_ws, size_t ws_size,
                              hipStream_t stream) {
    (void)in_sizes; (void)n_in; (void)out_size;
    const float* x = (const float*)d_in[0];
    const float* W = (const float*)d_in[1];
    float* out = (float*)d_out;

    if (ws_size < WS_NEED) return;
    char* ws = (char*)d_ws;
    ushort* u   = (ushort*)ws;
    float* Vsum = (float*)(ws + U_BYTES);
    float* s    = (float*)(ws + U_BYTES + V_BYTES);

    hipMemsetAsync(Vsum, 0, V_BYTES, stream);
    k_u<<<dim3(2048), dim3(256), 0, stream>>>(W, x, u);
    for (int it = 0; it < 3; ++it) {
        k_route<<<dim3(512), dim3(512), 0, stream>>>(u, Vsum, s);
        k_squash<<<dim3(512), dim3(256), 0, stream>>>(s, Vsum, out, it == 2);
    }
}

// Round 3
// 149.029 us; speedup vs baseline: 1.5576x; 1.3216x over previous
//
#include <hip/hip_runtime.h>

#define NB 32
#define NN 64
#define ND 128
#define NE 128
#define NK 64   // output capsules (= NN), contiguous axis of u/Vsum/s

typedef float  f32x4  __attribute__((ext_vector_type(4)));
typedef short  short8 __attribute__((ext_vector_type(8)));
typedef __bf16 bf16x8 __attribute__((ext_vector_type(8)));

union Frag { bf16x8 h; short8 s; };

static constexpr size_t U_BYTES = (size_t)NB * NN * ND * NK * 2;  // 33.5 MB bf16
static constexpr size_t V_BYTES = (size_t)NB * ND * NK * 4;       // 1 MB fp32
static constexpr size_t WS_NEED = U_BYTES + 2 * V_BYTES;

// ---------------- DPP wave64 sum (VALU pipe) ----------------
template <int CTRL, int RMASK>
__device__ __forceinline__ float dppf(float x) {
    int xi = __float_as_int(x);
    return __int_as_float(__builtin_amdgcn_update_dpp(xi, xi, CTRL, RMASK, 0xF, false));
}
__device__ __forceinline__ float wave_sum(float x) {
    x += dppf<0xB1, 0xF>(x);   // quad_perm [1,0,3,2]
    x += dppf<0x4E, 0xF>(x);   // quad_perm [2,3,0,1]
    x += dppf<0x141, 0xF>(x);  // row_half_mirror
    x += dppf<0x140, 0xF>(x);  // row_mirror
    x += dppf<0x142, 0xA>(x);  // row_bcast15 -> rows 1,3
    x += dppf<0x143, 0xC>(x);  // row_bcast31 -> rows 2,3
    return __int_as_float(__builtin_amdgcn_readlane(__float_as_int(x), 63));
}

__device__ __forceinline__ ushort f2bf(float f) {
    __bf16 h = (__bf16)f;
    ushort r;
    __builtin_memcpy(&r, &h, 2);
    return r;
}
__device__ __forceinline__ float bf2f(ushort r) {
    return __int_as_float(((int)r) << 16);
}
__device__ __forceinline__ void cvt8(const float4& a, const float4& b, Frag& fr) {
    fr.h[0] = (__bf16)a.x; fr.h[1] = (__bf16)a.y; fr.h[2] = (__bf16)a.z; fr.h[3] = (__bf16)a.w;
    fr.h[4] = (__bf16)b.x; fr.h[5] = (__bf16)b.y; fr.h[6] = (__bf16)b.z; fr.h[7] = (__bf16)b.w;
}

// ---------------- K1: u[b,j,d,k] = sum_e x[b,j,e] * W[j,k,d,e] (bf16 MFMA) --
// wave = (j,d): M=32 b's x N=64 k's, K=128 e's -> 32 x mfma 16x16x32_bf16
__global__ __launch_bounds__(256) void k_u(const float* __restrict__ W,
                                           const float* __restrict__ x,
                                           ushort* __restrict__ u) {
    __shared__ ushort T[4][32][72];  // per-wave [b][k] transpose tile
    const int t  = threadIdx.x;
    const int wv = t >> 6;
    const int l  = t & 63;
    const int gw = blockIdx.x * 4 + wv;
    const int j  = gw >> 7;
    const int d  = gw & 127;

    const int lr = l & 15;        // fragment row/col index
    const int e0 = (l >> 4) * 8;  // e-offset within K=32 chunk

    const float* xb = x + (size_t)j * NE;                     // + b*(NN*NE) + e
    const float* Wb = W + ((size_t)(j * NN) * ND + d) * NE;   // + k*(ND*NE) + e

    // A fragments: x[b, j, e], row = b
    Frag a[2][4];
#pragma unroll
    for (int mt = 0; mt < 2; ++mt)
#pragma unroll
        for (int ec = 0; ec < 4; ++ec) {
            const float* p = xb + (size_t)(mt * 16 + lr) * (NN * NE) + ec * 32 + e0;
            float4 f0 = *reinterpret_cast<const float4*>(p);
            float4 f1 = *reinterpret_cast<const float4*>(p + 4);
            cvt8(f0, f1, a[mt][ec]);
        }

    f32x4 acc[2][4];
#pragma unroll
    for (int mt = 0; mt < 2; ++mt)
#pragma unroll
        for (int nt = 0; nt < 4; ++nt) acc[mt][nt] = (f32x4)0.0f;

    // B fragments streamed from W (nontemporal: zero reuse, keep L3 for u)
#pragma unroll
    for (int nt = 0; nt < 4; ++nt) {
        Frag bw[4];
#pragma unroll
        for (int ec = 0; ec < 4; ++ec) {
            const float* p = Wb + (size_t)(nt * 16 + lr) * (ND * NE) + ec * 32 + e0;
            f32x4 g0 = __builtin_nontemporal_load(reinterpret_cast<const f32x4*>(p));
            f32x4 g1 = __builtin_nontemporal_load(reinterpret_cast<const f32x4*>(p + 4));
            float4 f0 = {g0[0], g0[1], g0[2], g0[3]};
            float4 f1 = {g1[0], g1[1], g1[2], g1[3]};
            cvt8(f0, f1, bw[ec]);
        }
#pragma unroll
        for (int ec = 0; ec < 4; ++ec)
#pragma unroll
            for (int mt = 0; mt < 2; ++mt)
                acc[mt][nt] = __builtin_amdgcn_mfma_f32_16x16x32_bf16(
                    a[mt][ec].s, bw[ec].s, acc[mt][nt], 0, 0, 0);
    }

    // D frag: row=b=(l>>4)*4+r (+16*mt), col=k=lr (+16*nt)  [m89 layout]
    const int lq = l >> 4;
#pragma unroll
    for (int mt = 0; mt < 2; ++mt)
#pragma unroll
        for (int nt = 0; nt < 4; ++nt)
#pragma unroll
            for (int r = 0; r < 4; ++r)
                T[wv][mt * 16 + lq * 4 + r][nt * 16 + lr] = f2bf(acc[mt][nt][r]);
    __syncthreads();

    // write u[b, j, d, :] rows (k-contiguous, 128 B/row)
    const int b2 = l >> 1;
    const int kh = (l & 1) * 32;
    ushort* up = u + (((size_t)b2 * NN + j) * ND + d) * NK + kh;
    const ushort* tp = &T[wv][b2][kh];
#pragma unroll
    for (int i = 0; i < 4; ++i) {
        short8 v = *reinterpret_cast<const short8*>(tp + i * 8);
        *reinterpret_cast<short8*>(up + i * 8) = v;
    }
}

// ---------------- Routing: s[b,d,k] = sum_j softmax_k(u*Vsum) * u ----------
// block = (b, dg of 8 d); 8 waves = 8 j-groups; lane = k
// first=1: logits are all zero -> exact uniform softmax, s = sum_j u / 64
// (never reads Vsum -> no memset needed, deterministic across replays)
__global__ __launch_bounds__(512) void k_route(const ushort* __restrict__ u,
                                               const float* __restrict__ Vsum,
                                               float* __restrict__ s,
                                               int first) {
    __shared__ float P[8][8][65];
    const int b  = blockIdx.x >> 4;
    const int dg = blockIdx.x & 15;
    const int t  = threadIdx.x;
    const int wv = t >> 6;  // j-group
    const int l  = t & 63;  // k

    float sacc[8];
#pragma unroll
    for (int dd = 0; dd < 8; ++dd) sacc[dd] = 0.0f;

    const ushort* ub = u + (((size_t)b * NN + wv * 8) * ND + dg * 8) * NK + l;

    if (first) {
        for (int jj = 0; jj < 8; ++jj) {
            const ushort* up = ub + (size_t)jj * (ND * NK);
#pragma unroll
            for (int dd = 0; dd < 8; ++dd) sacc[dd] += bf2f(up[dd * NK]);
        }
#pragma unroll
        for (int dd = 0; dd < 8; ++dd) sacc[dd] *= (1.0f / 64.0f);
    } else {
        float vs[8];
#pragma unroll
        for (int dd = 0; dd < 8; ++dd)
            vs[dd] = Vsum[((size_t)b * ND + dg * 8 + dd) * NK + l];

        for (int jj = 0; jj < 8; ++jj) {
            const ushort* up = ub + (size_t)jj * (ND * NK);
            float uv[8];
#pragma unroll
            for (int dd = 0; dd < 8; ++dd) uv[dd] = bf2f(up[dd * NK]);
#pragma unroll
            for (int dd = 0; dd < 8; ++dd) {
                // softmax is shift-invariant; constant shift avoids overflow
                // without a wave_max pass (|logit| realistically < ~45)
                float p = __expf(uv[dd] * vs[dd] - 32.0f);
                float q = wave_sum(p);
                sacc[dd] = fmaf(p * __builtin_amdgcn_rcpf(q), uv[dd], sacc[dd]);
            }
        }
    }

#pragma unroll
    for (int dd = 0; dd < 8; ++dd) P[wv][dd][l] = sacc[dd];
    __syncthreads();

    // 8-way j-group reduce; thread t -> (dd = t>>6, k = t&63)
    const int dd = t >> 6;
    const int k  = t & 63;
    float r = P[0][dd][k];
#pragma unroll
    for (int w2 = 1; w2 < 8; ++w2) r += P[w2][dd][k];
    s[((size_t)b * ND + dg * 8 + dd) * NK + k] = r;
}

// ---------------- Squash: wave=(b,k), lane=d -------------------------------
// mode 0: Vsum = v (init, no read)   mode 1: Vsum += v   mode 2: out = v
__global__ __launch_bounds__(256) void k_squash(const float* __restrict__ s,
                                                float* __restrict__ Vsum,
                                                float* __restrict__ out,
                                                int mode) {
    const int t  = threadIdx.x;
    const int gw = blockIdx.x * 4 + (t >> 6);
    const int b  = gw >> 6;
    const int k  = gw & 63;
    const int l  = t & 63;

    const float s0 = s[((size_t)b * ND + l) * NK + k];
    const float s1 = s[((size_t)b * ND + l + 64) * NK + k];
    float sq    = wave_sum(fmaf(s0, s0, s1 * s1));
    float scale = (sq / (1.0f + sq)) * rsqrtf(sq + 1e-9f);
    float v0 = s0 * scale, v1 = s1 * scale;
    if (mode == 2) {
        float* op = out + ((size_t)b * NN + k) * ND;  // out[b,k,d] contiguous in d
        op[l]      = v0;
        op[l + 64] = v1;
    } else if (mode == 0) {
        float* vp = Vsum + (size_t)b * ND * NK + k;
        vp[(size_t)l * NK]        = v0;
        vp[(size_t)(l + 64) * NK] = v1;
    } else {
        float* vp = Vsum + (size_t)b * ND * NK + k;
        vp[(size_t)l * NK]        += v0;
        vp[(size_t)(l + 64) * NK] += v1;
    }
}

extern "C" void kernel_launch(void* const* d_in, const int* in_sizes, int n_in,
                              void* d_out, int out_size, void* d_ws, size_t ws_size,
                              hipStream_t stream) {
    (void)in_sizes; (void)n_in; (void)out_size;
    const float* x = (const float*)d_in[0];
    const float* W = (const float*)d_in[1];
    float* out = (float*)d_out;

    if (ws_size < WS_NEED) return;
    char* ws = (char*)d_ws;
    ushort* u   = (ushort*)ws;
    float* Vsum = (float*)(ws + U_BYTES);
    float* s    = (float*)(ws + U_BYTES + V_BYTES);

    k_u<<<dim3(2048), dim3(256), 0, stream>>>(W, x, u);
    for (int it = 0; it < 3; ++it) {
        k_route<<<dim3(512), dim3(512), 0, stream>>>(u, Vsum, s, it == 0 ? 1 : 0);
        k_squash<<<dim3(512), dim3(256), 0, stream>>>(s, Vsum, out, it);
    }
}

// Round 4
// 123.264 us; speedup vs baseline: 1.8832x; 1.2090x over previous
//
#include <hip/hip_runtime.h>

#define NB 32
#define NN 64
#define ND 128
#define NE 128
#define NK 64   // output capsules (= NN), contiguous axis of u/Vsum/s

typedef float  f32x4  __attribute__((ext_vector_type(4)));
typedef short  short8 __attribute__((ext_vector_type(8)));
typedef __bf16 bf16x8 __attribute__((ext_vector_type(8)));

union Frag { bf16x8 h; short8 s; };

static constexpr size_t U_BYTES = (size_t)NB * NN * ND * NK * 2;  // 33.5 MB bf16
static constexpr size_t V_BYTES = (size_t)NB * ND * NK * 4;       // 1 MB fp32
static constexpr size_t WS_NEED = U_BYTES + 2 * V_BYTES;

#define GLOAD16(g, l)                                                   \
    __builtin_amdgcn_global_load_lds(                                   \
        (const __attribute__((address_space(1))) void*)(g),             \
        (__attribute__((address_space(3))) void*)(l), 16, 0, 0)

// ---------------- DPP wave64 sum (VALU pipe) ----------------
template <int CTRL, int RMASK>
__device__ __forceinline__ float dppf(float x) {
    int xi = __float_as_int(x);
    return __int_as_float(__builtin_amdgcn_update_dpp(xi, xi, CTRL, RMASK, 0xF, false));
}
__device__ __forceinline__ float wave_sum(float x) {
    x += dppf<0xB1, 0xF>(x);   // quad_perm [1,0,3,2]
    x += dppf<0x4E, 0xF>(x);   // quad_perm [2,3,0,1]
    x += dppf<0x141, 0xF>(x);  // row_half_mirror
    x += dppf<0x140, 0xF>(x);  // row_mirror
    x += dppf<0x142, 0xA>(x);  // row_bcast15 -> rows 1,3
    x += dppf<0x143, 0xC>(x);  // row_bcast31 -> rows 2,3
    return __int_as_float(__builtin_amdgcn_readlane(__float_as_int(x), 63));
}

__device__ __forceinline__ ushort f2bf(float f) {
    __bf16 h = (__bf16)f;
    ushort r;
    __builtin_memcpy(&r, &h, 2);
    return r;
}
__device__ __forceinline__ float bf2f(ushort r) {
    return __int_as_float(((int)r) << 16);
}
__device__ __forceinline__ void cvt8(const float4& a, const float4& b, Frag& fr) {
    fr.h[0] = (__bf16)a.x; fr.h[1] = (__bf16)a.y; fr.h[2] = (__bf16)a.z; fr.h[3] = (__bf16)a.w;
    fr.h[4] = (__bf16)b.x; fr.h[5] = (__bf16)b.y; fr.h[6] = (__bf16)b.z; fr.h[7] = (__bf16)b.w;
}

// ---------------- K1: u[b,j,d,k] = sum_e x[b,j,e] * W[j,k,d,e] (bf16 MFMA) --
// wave = (j,d): M=32 b x N=64 k, K=128 e -> 32 x mfma 16x16x32_bf16.
// W staged global->LDS via global_load_lds (deep async queue), e-major layout
// (transpose during staging via per-lane source addrs) -> conflict-free reads.
__global__ __launch_bounds__(256, 3) void k_u(const float* __restrict__ W,
                                              const float* __restrict__ x,
                                              ushort* __restrict__ u) {
    __shared__ float  Wl[4][2][1024];  // per-wave double-buffered 4KB chunks
    __shared__ ushort T[4][32][72];    // per-wave [b][k] transpose tile
    const int t  = threadIdx.x;
    const int wv = t >> 6;
    const int l  = t & 63;
    const int gw = blockIdx.x * 4 + wv;
    const int j  = gw >> 7;
    const int d  = gw & 127;

    const int lr = l & 15;  // fragment row/col index
    const int lh = l >> 4;  // 0..3
    const int e0 = lh * 8;

    // ---- A fragments: x[b, j, e], row = b (VGPR loads; x is small & L2-hot)
    const float* xb = x + (size_t)j * NE;
    float4 xf[2][4][2];
#pragma unroll
    for (int mt = 0; mt < 2; ++mt)
#pragma unroll
        for (int ec = 0; ec < 4; ++ec) {
            const float* p = xb + (size_t)(mt * 16 + lr) * (NN * NE) + ec * 32 + e0;
            xf[mt][ec][0] = *reinterpret_cast<const float4*>(p);
            xf[mt][ec][1] = *reinterpret_cast<const float4*>(p + 4);
        }
    // drain A-loads so chunk vmcnt bookkeeping below is exact
    asm volatile("s_waitcnt vmcnt(0)" ::: "memory");
    __builtin_amdgcn_sched_barrier(0);
    Frag a[2][4];
#pragma unroll
    for (int mt = 0; mt < 2; ++mt)
#pragma unroll
        for (int ec = 0; ec < 4; ++ec) cvt8(xf[mt][ec][0], xf[mt][ec][1], a[mt][ec]);

    // ---- W staging: chunk c=(nt,eh): k rows nt*16..+15, e floats eh*64..+63
    // LDS e-major: slot = e16*16 + row; instr i, lane l -> slot i*64+l, so
    // source = (row=l&15, e16=i*4+l>>4). 4 x GLOAD16 (1KB each) per chunk.
    const char* Wg = (const char*)W + ((size_t)(j * NN) * ND + d) * (NE * 4);
#define STAGE(c, buf)                                                       \
    {                                                                       \
        const int nt_ = (c) >> 1, eh_ = (c) & 1;                            \
        const char* gp_ = Wg + (size_t)(nt_ * 16 + lr) * 65536 + eh_ * 256; \
        _Pragma("unroll") for (int i_ = 0; i_ < 4; ++i_)                    \
            GLOAD16(gp_ + (i_ * 4 + lh) * 16, &Wl[wv][buf][i_ * 256]);      \
    }

    STAGE(0, 0);
    STAGE(1, 1);

    f32x4 acc[2][4];
#pragma unroll
    for (int mt = 0; mt < 2; ++mt)
#pragma unroll
        for (int nt = 0; nt < 4; ++nt) acc[mt][nt] = (f32x4)0.0f;

#pragma unroll
    for (int c = 0; c < 8; ++c) {
        const int nt = c >> 1, eh = c & 1, buf = c & 1;
        if (c < 7) { asm volatile("s_waitcnt vmcnt(4)" ::: "memory"); }
        else       { asm volatile("s_waitcnt vmcnt(0)" ::: "memory"); }
        __builtin_amdgcn_sched_barrier(0);

        const float* cb = &Wl[wv][buf][0];
        f32x4 g[2][2];
#pragma unroll
        for (int ec = 0; ec < 2; ++ec) {
            const int sl = (ec * 8 + lh * 2) * 64 + lr * 4;
            g[ec][0] = *reinterpret_cast<const f32x4*>(cb + sl);
            g[ec][1] = *reinterpret_cast<const f32x4*>(cb + sl + 64);
        }
        // ds_reads must land before this buffer is re-staged (rule #18)
        asm volatile("s_waitcnt lgkmcnt(0)" ::: "memory");
        __builtin_amdgcn_sched_barrier(0);
        if (c < 6) STAGE(c + 2, buf);

#pragma unroll
        for (int ec = 0; ec < 2; ++ec) {
            Frag bw;
            float4 f0 = {g[ec][0][0], g[ec][0][1], g[ec][0][2], g[ec][0][3]};
            float4 f1 = {g[ec][1][0], g[ec][1][1], g[ec][1][2], g[ec][1][3]};
            cvt8(f0, f1, bw);
#pragma unroll
            for (int mt = 0; mt < 2; ++mt)
                acc[mt][nt] = __builtin_amdgcn_mfma_f32_16x16x32_bf16(
                    a[mt][eh * 2 + ec].s, bw.s, acc[mt][nt], 0, 0, 0);
        }
    }
#undef STAGE

    // D frag: row=b=(l>>4)*4+r (+16*mt), col=k=lr (+16*nt)  [m89 layout]
#pragma unroll
    for (int mt = 0; mt < 2; ++mt)
#pragma unroll
        for (int nt = 0; nt < 4; ++nt)
#pragma unroll
            for (int r = 0; r < 4; ++r)
                T[wv][mt * 16 + lh * 4 + r][nt * 16 + lr] = f2bf(acc[mt][nt][r]);
    __syncthreads();

    // write u[b, j, d, :] rows (k-contiguous, 128 B/row)
    const int b2 = l >> 1;
    const int kh = (l & 1) * 32;
    ushort* up = u + (((size_t)b2 * NN + j) * ND + d) * NK + kh;
    const ushort* tp = &T[wv][b2][kh];
#pragma unroll
    for (int i = 0; i < 4; ++i) {
        short8 v = *reinterpret_cast<const short8*>(tp + i * 8);
        *reinterpret_cast<short8*>(up + i * 8) = v;
    }
}

// ---------------- Routing: s[b,d,k] = sum_j softmax_k(u*Vsum) * u ----------
// block = (b, dg of 8 d); 8 waves = 8 j-groups; lane = k
// first=1: logits all zero -> exact uniform softmax, s = sum_j u / 64
__global__ __launch_bounds__(512) void k_route(const ushort* __restrict__ u,
                                               const float* __restrict__ Vsum,
                                               float* __restrict__ s,
                                               int first) {
    __shared__ float P[8][8][65];
    const int b  = blockIdx.x >> 4;
    const int dg = blockIdx.x & 15;
    const int t  = threadIdx.x;
    const int wv = t >> 6;  // j-group
    const int l  = t & 63;  // k

    float sacc[8];
#pragma unroll
    for (int dd = 0; dd < 8; ++dd) sacc[dd] = 0.0f;

    const ushort* ub = u + (((size_t)b * NN + wv * 8) * ND + dg * 8) * NK + l;

    if (first) {
        for (int jj = 0; jj < 8; ++jj) {
            const ushort* up = ub + (size_t)jj * (ND * NK);
#pragma unroll
            for (int dd = 0; dd < 8; ++dd) sacc[dd] += bf2f(up[dd * NK]);
        }
#pragma unroll
        for (int dd = 0; dd < 8; ++dd) sacc[dd] *= (1.0f / 64.0f);
    } else {
        float vs[8];
#pragma unroll
        for (int dd = 0; dd < 8; ++dd)
            vs[dd] = Vsum[((size_t)b * ND + dg * 8 + dd) * NK + l];

        for (int jj = 0; jj < 8; ++jj) {
            const ushort* up = ub + (size_t)jj * (ND * NK);
            float uv[8];
#pragma unroll
            for (int dd = 0; dd < 8; ++dd) uv[dd] = bf2f(up[dd * NK]);
#pragma unroll
            for (int dd = 0; dd < 8; ++dd) {
                // softmax is shift-invariant; constant shift avoids overflow
                // without a wave_max pass (|logit| realistically < ~45)
                float p = __expf(uv[dd] * vs[dd] - 32.0f);
                float q = wave_sum(p);
                sacc[dd] = fmaf(p * __builtin_amdgcn_rcpf(q), uv[dd], sacc[dd]);
            }
        }
    }

#pragma unroll
    for (int dd = 0; dd < 8; ++dd) P[wv][dd][l] = sacc[dd];
    __syncthreads();

    // 8-way j-group reduce; thread t -> (dd = t>>6, k = t&63)
    const int dd = t >> 6;
    const int k  = t & 63;
    float r = P[0][dd][k];
#pragma unroll
    for (int w2 = 1; w2 < 8; ++w2) r += P[w2][dd][k];
    s[((size_t)b * ND + dg * 8 + dd) * NK + k] = r;
}

// ---------------- Squash: wave=(b,k), lane=d -------------------------------
// mode 0: Vsum = v (init, no read)   mode 1: Vsum += v   mode 2: out = v
__global__ __launch_bounds__(256) void k_squash(const float* __restrict__ s,
                                                float* __restrict__ Vsum,
                                                float* __restrict__ out,
                                                int mode) {
    const int t  = threadIdx.x;
    const int gw = blockIdx.x * 4 + (t >> 6);
    const int b  = gw >> 6;
    const int k  = gw & 63;
    const int l  = t & 63;

    const float s0 = s[((size_t)b * ND + l) * NK + k];
    const float s1 = s[((size_t)b * ND + l + 64) * NK + k];
    float sq    = wave_sum(fmaf(s0, s0, s1 * s1));
    float scale = (sq / (1.0f + sq)) * rsqrtf(sq + 1e-9f);
    float v0 = s0 * scale, v1 = s1 * scale;
    if (mode == 2) {
        float* op = out + ((size_t)b * NN + k) * ND;  // out[b,k,d] contiguous in d
        op[l]      = v0;
        op[l + 64] = v1;
    } else if (mode == 0) {
        float* vp = Vsum + (size_t)b * ND * NK + k;
        vp[(size_t)l * NK]        = v0;
        vp[(size_t)(l + 64) * NK] = v1;
    } else {
        float* vp = Vsum + (size_t)b * ND * NK + k;
        vp[(size_t)l * NK]        += v0;
        vp[(size_t)(l + 64) * NK] += v1;
    }
}

extern "C" void kernel_launch(void* const* d_in, const int* in_sizes, int n_in,
                              void* d_out, int out_size, void* d_ws, size_t ws_size,
                              hipStream_t stream) {
    (void)in_sizes; (void)n_in; (void)out_size;
    const float* x = (const float*)d_in[0];
    const float* W = (const float*)d_in[1];
    float* out = (float*)d_out;

    if (ws_size < WS_NEED) return;
    char* ws = (char*)d_ws;
    ushort* u   = (ushort*)ws;
    float* Vsum = (float*)(ws + U_BYTES);
    float* s    = (float*)(ws + U_BYTES + V_BYTES);

    k_u<<<dim3(2048), dim3(256), 0, stream>>>(W, x, u);
    for (int it = 0; it < 3; ++it) {
        k_route<<<dim3(512), dim3(512), 0, stream>>>(u, Vsum, s, it == 0 ? 1 : 0);
        k_squash<<<dim3(512), dim3(256), 0, stream>>>(s, Vsum, out, it);
    }
}